// Round 4
// baseline (232.700 us; speedup 1.0000x reference)
//
#include <hip/hip_runtime.h>
#include <hip/hip_bf16.h>

#define NPTS   10000
#define NRAYS  4096
#define CHUNKS 64
#define CPTS   ((NPTS + CHUNKS - 1) / CHUNKS)   // 157

// ---- static device scratch (no d_ws dependency) ----
__device__ float g_pts [NPTS * 56];   // x,y,z,delta,w0, sh_r[16], sh_g[16], sh_b[16], pad3
__device__ float g_rays[NRAYS * 24];  // ox,oy,oz, dx,dy,dz, sh[16], pad2
__device__ float g_acc [NRAYS * 5];   // Sr,Sg,Sb,Sd,S
__device__ float g_opsum;

__device__ __forceinline__ float fast_rcp(float x)  { return __builtin_amdgcn_rcpf(x); }
__device__ __forceinline__ float fast_sigmoid(float x) { return fast_rcp(1.0f + __expf(-x)); }

// ---------------- Kernel 1: per-ray precompute + zero accumulators -----------
__global__ void precompute_rays(const float* __restrict__ ro,
                                const float* __restrict__ rd) {
    int r = blockIdx.x * blockDim.x + threadIdx.x;
    if (r >= NRAYS) return;

    // zero accumulators for this call
    float* a = g_acc + (size_t)r * 5;
    a[0] = a[1] = a[2] = a[3] = a[4] = 0.0f;
    if (r == 0) g_opsum = 0.0f;

    float ox = ro[r * 3 + 0], oy = ro[r * 3 + 1], oz = ro[r * 3 + 2];
    float dx = rd[r * 3 + 0], dy = rd[r * 3 + 1], dz = rd[r * 3 + 2];
    float inv = __builtin_amdgcn_rsqf(dx * dx + dy * dy + dz * dz);
    float x = dx * inv, y = dy * inv, z = dz * inv;
    float* o = g_rays + (size_t)r * 24;
    o[0] = ox; o[1] = oy; o[2] = oz;
    o[3] = x;  o[4] = y;  o[5] = z;
    float* sh = o + 6;
    float zz = z * z, xx = x * x, yy = y * y;
    sh[0]  = 0.282095f;
    sh[1]  = 0.488603f * y;
    sh[2]  = 0.488603f * z;
    sh[3]  = 0.488603f * x;
    sh[4]  = 1.092548f * x * y;
    sh[5]  = 1.092548f * y * z;
    sh[6]  = 0.315392f * (3.0f * zz - 1.0f);
    sh[7]  = 1.092548f * x * z;
    sh[8]  = 0.546274f * (xx - yy);
    sh[9]  = 0.590044f * y * (3.0f * xx - yy);
    sh[10] = 2.890611f * x * y * z;
    sh[11] = 0.457046f * y * (5.0f * zz - 1.0f);
    sh[12] = 0.373176f * z * (5.0f * zz - 3.0f);
    sh[13] = 0.457046f * x * (5.0f * zz - 1.0f);
    sh[14] = 1.445306f * z * (xx - yy);
    sh[15] = 0.590044f * x * (xx - 3.0f * yy);
}

// ---------------- Kernel 2: per-point precompute -----------------------------
__global__ void precompute_points(const float* __restrict__ pos,
                                  const int*   __restrict__ sidx,
                                  const float* __restrict__ log_delta,
                                  const float* __restrict__ log_sigma,
                                  const float* __restrict__ raw_op,
                                  const float* __restrict__ shc) {
    int n = blockIdx.x * blockDim.x + threadIdx.x;
    float op = 0.0f;
    if (n < NPTS) {
        float* o = g_pts + (size_t)n * 56;
        o[0] = pos[n * 3 + 0];
        o[1] = pos[n * 3 + 1];
        o[2] = pos[n * 3 + 2];
        int s = sidx[n];
        op = fast_sigmoid(raw_op[n]);
        o[3] = __expf(log_delta[s]);          // delta
        o[4] = __expf(log_sigma[s]) * op;     // sigma * opacity folded
        const float* c = shc + (size_t)n * 48;
#pragma unroll
        for (int k = 0; k < 16; ++k) {        // [k][c] -> channel-major
            o[5 + k]  = c[k * 3 + 0];
            o[21 + k] = c[k * 3 + 1];
            o[37 + k] = c[k * 3 + 2];
        }
    }
    // wave-reduce opacity, one atomic per wave (for the opacity-mean output)
    float v = op;
#pragma unroll
    for (int off = 32; off > 0; off >>= 1) v += __shfl_down(v, off, 64);
    if ((threadIdx.x & 63) == 0) atomicAdd(&g_opsum, v);
}

// ---------------- Kernel 3: main (ray-thread x point-chunk blocks) -----------
__global__ __launch_bounds__(256) void nerf_main() {
    int rb = blockIdx.x & 15;     // 16 ray blocks of 256 rays
    int ch = blockIdx.x >> 4;     // 64 point chunks
    int r  = rb * 256 + threadIdx.x;

    const float* rp = g_rays + (size_t)r * 24;
    float ox = rp[0], oy = rp[1], oz = rp[2];
    float dx = rp[3], dy = rp[4], dz = rp[5];
    float sh[16];
#pragma unroll
    for (int k = 0; k < 16; ++k) sh[k] = rp[6 + k];

    int p0 = ch * CPTS;
    int p1 = min(NPTS, p0 + CPTS);

    float S = 0.0f, Sd = 0.0f, Sr = 0.0f, Sg = 0.0f, Sb = 0.0f;
    for (int p = p0; p < p1; ++p) {
        const float* q = g_pts + (size_t)p * 56;   // wave-uniform -> scalar loads
        float px = q[0], py = q[1], pz = q[2];
        float delta = q[3], w0 = q[4];

        float rx = px - ox, ry = py - oy, rz = pz - oz;
        float d2 = rx * rx + ry * ry + rz * rz;
        float dist = __builtin_amdgcn_sqrtf(d2);
        float inv  = fast_rcp(dist + 1e-6f);      // shared for dir-norm & 1/dist
        float dot  = (rx * dx + ry * dy + rz * dz) * inv;
        float t    = 1.0f - dot;
        float contrib = __expf(-delta * t * t) * w0 * inv;

        S  += contrib;
        Sd += dist * contrib;

        float s0 = 0.0f, s1 = 0.0f, s2 = 0.0f;
#pragma unroll
        for (int k = 0; k < 16; ++k) {
            s0 += q[5 + k]  * sh[k];
            s1 += q[21 + k] * sh[k];
            s2 += q[37 + k] * sh[k];
        }
        Sr += fast_sigmoid(s0) * contrib;
        Sg += fast_sigmoid(s1) * contrib;
        Sb += fast_sigmoid(s2) * contrib;
    }

    float* a = g_acc + (size_t)r * 5;
    atomicAdd(a + 0, Sr);
    atomicAdd(a + 1, Sg);
    atomicAdd(a + 2, Sb);
    atomicAdd(a + 3, Sd);
    atomicAdd(a + 4, S);
}

// ---------------- Kernel 4: finalize (f32 output, matching reference dtype) --
__global__ void finalize(float* __restrict__ out) {
    int r = blockIdx.x * blockDim.x + threadIdx.x;
    if (r >= NRAYS) return;
    const float* a = g_acc + (size_t)r * 5;
    float inv = fast_rcp(a[4] + 1e-8f);
    out[r * 3 + 0]     = a[0] * inv;
    out[r * 3 + 1]     = a[1] * inv;
    out[r * 3 + 2]     = a[2] * inv;
    out[NRAYS * 3 + r] = a[3] * inv;
    out[NRAYS * 4 + r] = g_opsum * (1.0f / NPTS);
}

extern "C" void kernel_launch(void* const* d_in, const int* in_sizes, int n_in,
                              void* d_out, int out_size, void* d_ws, size_t ws_size,
                              hipStream_t stream) {
    const float* rays_o    = (const float*)d_in[0];
    const float* rays_d    = (const float*)d_in[1];
    const float* positions = (const float*)d_in[2];
    const int*   sidx      = (const int*)d_in[3];
    const float* log_delta = (const float*)d_in[4];
    const float* log_sigma = (const float*)d_in[5];
    const float* raw_op    = (const float*)d_in[6];
    const float* shc       = (const float*)d_in[7];

    precompute_rays<<<NRAYS / 256, 256, 0, stream>>>(rays_o, rays_d);
    precompute_points<<<(NPTS + 255) / 256, 256, 0, stream>>>(
        positions, sidx, log_delta, log_sigma, raw_op, shc);
    nerf_main<<<16 * CHUNKS, 256, 0, stream>>>();
    finalize<<<NRAYS / 256, 256, 0, stream>>>((float*)d_out);
}

// Round 5
// 202.973 us; speedup vs baseline: 1.1465x; 1.1465x over previous
//
#include <hip/hip_runtime.h>
#include <hip/hip_bf16.h>

#define NPTS   10000
#define NRAYS  4096
#define CHUNKS 128
#define CPTS   ((NPTS + CHUNKS - 1) / CHUNKS)   // 79
#define LOG2E  1.44269504f

// ---- static device scratch ----
// g_geo: x,y,z, w1(=-delta*log2e), w0(=sigma*opacity), pad3  (8 dwords/point)
__device__ float g_geo [NPTS * 8];
__device__ float g_rays[NRAYS * 24];  // ox,oy,oz, dx,dy,dz, sh[16], pad2
__device__ float g_acc [NRAYS * 5];   // Sr,Sg,Sb,Sd,S
__device__ float g_opsum;

__device__ __forceinline__ float fast_rcp(float x)  { return __builtin_amdgcn_rcpf(x); }
__device__ __forceinline__ float fast_exp2(float x) { return __builtin_amdgcn_exp2f(x); }
__device__ __forceinline__ float fast_sigmoid(float x) { return fast_rcp(1.0f + fast_exp2(-x * LOG2E)); }

// ---------------- Kernel 1: per-ray precompute + zero accumulators -----------
__global__ void precompute_rays(const float* __restrict__ ro,
                                const float* __restrict__ rd) {
    int r = blockIdx.x * blockDim.x + threadIdx.x;
    if (r >= NRAYS) return;

    float* a = g_acc + (size_t)r * 5;
    a[0] = a[1] = a[2] = a[3] = a[4] = 0.0f;
    if (r == 0) g_opsum = 0.0f;

    float ox = ro[r * 3 + 0], oy = ro[r * 3 + 1], oz = ro[r * 3 + 2];
    float dx = rd[r * 3 + 0], dy = rd[r * 3 + 1], dz = rd[r * 3 + 2];
    float inv = __builtin_amdgcn_rsqf(dx * dx + dy * dy + dz * dz);
    float x = dx * inv, y = dy * inv, z = dz * inv;
    float* o = g_rays + (size_t)r * 24;
    o[0] = ox; o[1] = oy; o[2] = oz;
    o[3] = x;  o[4] = y;  o[5] = z;
    float* sh = o + 6;
    float zz = z * z, xx = x * x, yy = y * y;
    sh[0]  = 0.282095f;
    sh[1]  = 0.488603f * y;
    sh[2]  = 0.488603f * z;
    sh[3]  = 0.488603f * x;
    sh[4]  = 1.092548f * x * y;
    sh[5]  = 1.092548f * y * z;
    sh[6]  = 0.315392f * (3.0f * zz - 1.0f);
    sh[7]  = 1.092548f * x * z;
    sh[8]  = 0.546274f * (xx - yy);
    sh[9]  = 0.590044f * y * (3.0f * xx - yy);
    sh[10] = 2.890611f * x * y * z;
    sh[11] = 0.457046f * y * (5.0f * zz - 1.0f);
    sh[12] = 0.373176f * z * (5.0f * zz - 3.0f);
    sh[13] = 0.457046f * x * (5.0f * zz - 1.0f);
    sh[14] = 1.445306f * z * (xx - yy);
    sh[15] = 0.590044f * x * (xx - 3.0f * yy);
}

// ---------------- Kernel 2: per-point geo precompute (5 dwords out) ----------
__global__ void precompute_points(const float* __restrict__ pos,
                                  const int*   __restrict__ sidx,
                                  const float* __restrict__ log_delta,
                                  const float* __restrict__ log_sigma,
                                  const float* __restrict__ raw_op) {
    int n = blockIdx.x * blockDim.x + threadIdx.x;
    float op = 0.0f;
    if (n < NPTS) {
        float* o = g_geo + (size_t)n * 8;
        o[0] = pos[n * 3 + 0];
        o[1] = pos[n * 3 + 1];
        o[2] = pos[n * 3 + 2];
        int s = sidx[n];
        op = fast_sigmoid(raw_op[n]);
        o[3] = -__expf(log_delta[s]) * LOG2E;   // w1: exp arg premultiplier
        o[4] =  __expf(log_sigma[s]) * op;      // w0: sigma * opacity
    }
    float v = op;
#pragma unroll
    for (int off = 32; off > 0; off >>= 1) v += __shfl_down(v, off, 64);
    if ((threadIdx.x & 63) == 0) atomicAdd(&g_opsum, v);
}

// ---------------- Kernel 3: main (ray-thread x point-chunk blocks) -----------
__global__ __launch_bounds__(256) void nerf_main(const float* __restrict__ shc) {
    int rb = blockIdx.x & 15;     // 16 ray blocks of 256 rays
    int ch = blockIdx.x >> 4;     // CHUNKS point chunks
    int r  = rb * 256 + threadIdx.x;

    const float* rp = g_rays + (size_t)r * 24;
    float ox = rp[0], oy = rp[1], oz = rp[2];
    float dx = rp[3], dy = rp[4], dz = rp[5];
    float sh[16];
#pragma unroll
    for (int k = 0; k < 16; ++k) sh[k] = rp[6 + k];

    int p0 = ch * CPTS;
    int p1 = min(NPTS, p0 + CPTS);

    float S = 0.0f, Sd = 0.0f, Sr = 0.0f, Sg = 0.0f, Sb = 0.0f;
    for (int p = p0; p < p1; ++p) {
        const float* q = g_geo + (size_t)p * 8;    // wave-uniform -> s_load
        const float* c = shc   + (size_t)p * 48;   // SH coeffs read directly
        float px = q[0], py = q[1], pz = q[2];
        float w1 = q[3], w0 = q[4];

        float rx = px - ox, ry = py - oy, rz = pz - oz;
        float d2  = rx * rx + ry * ry + rz * rz;
        float inv = __builtin_amdgcn_rsqf(d2);     // ~1/dist (eps negligible)
        float dist = d2 * inv;
        float dn  = rx * dx + ry * dy + rz * dz;
        float t   = 1.0f - dn * inv;
        float contrib = fast_exp2(w1 * t * t) * w0 * inv;

        S  += contrib;
        Sd += dist * contrib;

        float s0 = 0.0f, s1 = 0.0f, s2 = 0.0f;
#pragma unroll
        for (int k = 0; k < 16; ++k) {
            s0 += c[k * 3 + 0] * sh[k];
            s1 += c[k * 3 + 1] * sh[k];
            s2 += c[k * 3 + 2] * sh[k];
        }
        // three sigmoids with a single reciprocal:
        // sigma(s)*contrib = contrib / (1+e^-s); batch the three denominators.
        float a0 = 1.0f + fast_exp2(-s0 * LOG2E);
        float a1 = 1.0f + fast_exp2(-s1 * LOG2E);
        float a2 = 1.0f + fast_exp2(-s2 * LOG2E);
        float ab  = a0 * a1;
        float CI  = contrib * fast_rcp(ab * a2);
        Sr += CI * (a1 * a2);
        Sg += CI * (a0 * a2);
        Sb += CI * ab;
    }

    float* a = g_acc + (size_t)r * 5;
    atomicAdd(a + 0, Sr);
    atomicAdd(a + 1, Sg);
    atomicAdd(a + 2, Sb);
    atomicAdd(a + 3, Sd);
    atomicAdd(a + 4, S);
}

// ---------------- Kernel 4: finalize (f32 output) ----------------------------
__global__ void finalize(float* __restrict__ out) {
    int r = blockIdx.x * blockDim.x + threadIdx.x;
    if (r >= NRAYS) return;
    const float* a = g_acc + (size_t)r * 5;
    float inv = fast_rcp(a[4] + 1e-8f);
    out[r * 3 + 0]     = a[0] * inv;
    out[r * 3 + 1]     = a[1] * inv;
    out[r * 3 + 2]     = a[2] * inv;
    out[NRAYS * 3 + r] = a[3] * inv;
    out[NRAYS * 4 + r] = g_opsum * (1.0f / NPTS);
}

extern "C" void kernel_launch(void* const* d_in, const int* in_sizes, int n_in,
                              void* d_out, int out_size, void* d_ws, size_t ws_size,
                              hipStream_t stream) {
    const float* rays_o    = (const float*)d_in[0];
    const float* rays_d    = (const float*)d_in[1];
    const float* positions = (const float*)d_in[2];
    const int*   sidx      = (const int*)d_in[3];
    const float* log_delta = (const float*)d_in[4];
    const float* log_sigma = (const float*)d_in[5];
    const float* raw_op    = (const float*)d_in[6];
    const float* shc       = (const float*)d_in[7];

    precompute_rays<<<NRAYS / 256, 256, 0, stream>>>(rays_o, rays_d);
    precompute_points<<<(NPTS + 255) / 256, 256, 0, stream>>>(
        positions, sidx, log_delta, log_sigma, raw_op);
    nerf_main<<<16 * CHUNKS, 256, 0, stream>>>(shc);
    finalize<<<NRAYS / 256, 256, 0, stream>>>((float*)d_out);
}

// Round 6
// 192.802 us; speedup vs baseline: 1.2069x; 1.0528x over previous
//
#include <hip/hip_runtime.h>

#define NPTS      10000
#define NPTS_PAD  10240          // 128 chunks x 40 pairs x 2
#define NRAYS     4096
#define CHUNKS    128
#define PAIRS     40             // pairs per chunk
#define NPAIRS    (NPTS_PAD / 2) // 5120
#define PT_BLOCKS (NPTS_PAD / 256) // 40
#define LOG2E     1.44269504f

typedef float v2 __attribute__((ext_vector_type(2)));

// ---- static device scratch ----
// g_geo : per pair, 16 floats: x0,x1, y0,y1, z0,z1, w1_0,w1_1, w0_0,w0_1, pad6
//         (w1 = -delta*log2e, w0 = sigma*opacity)
__device__ float g_geo [NPAIRS * 16];
// g_shc : per pair, 96 floats: (k*3+ch)*2 + point-in-pair
__device__ float g_shc [NPAIRS * 96];
__device__ float g_rays[NRAYS * 24];   // ox,oy,oz, dx,dy,dz, sh[16], pad2
__device__ float g_acc [NRAYS * 5];    // Sr,Sg,Sb,Sd,S
__device__ float g_oppart[PT_BLOCKS];  // per-block opacity partial sums

__device__ __forceinline__ float fast_rcp(float x)  { return __builtin_amdgcn_rcpf(x); }
__device__ __forceinline__ float fast_exp2(float x) { return __builtin_amdgcn_exp2f(x); }
__device__ __forceinline__ float fast_sigmoid(float x) { return fast_rcp(1.0f + fast_exp2(-x * LOG2E)); }

__device__ __forceinline__ v2 v2splat(float s) { v2 r; r.x = s; r.y = s; return r; }
__device__ __forceinline__ v2 fmav(v2 a, v2 b, v2 c) { return __builtin_elementwise_fma(a, b, c); }
__device__ __forceinline__ v2 exp2v(v2 a) { v2 r; r.x = fast_exp2(a.x); r.y = fast_exp2(a.y); return r; }
__device__ __forceinline__ v2 rsqv(v2 a)  { v2 r; r.x = __builtin_amdgcn_rsqf(a.x); r.y = __builtin_amdgcn_rsqf(a.y); return r; }
__device__ __forceinline__ v2 rcpv(v2 a)  { v2 r; r.x = fast_rcp(a.x); r.y = fast_rcp(a.y); return r; }

// ---------------- Kernel 1: merged setup (rays + points) ---------------------
// blocks 0..15: per-ray precompute + g_acc zero
// blocks 16..55: per-point precompute into pair-interleaved layout + opacity partials
__global__ __launch_bounds__(256) void setup(const float* __restrict__ ro,
                                             const float* __restrict__ rd,
                                             const float* __restrict__ pos,
                                             const int*   __restrict__ sidx,
                                             const float* __restrict__ log_delta,
                                             const float* __restrict__ log_sigma,
                                             const float* __restrict__ raw_op,
                                             const float* __restrict__ shc) {
    if (blockIdx.x < 16) {
        int r = blockIdx.x * 256 + threadIdx.x;
        float* a = g_acc + (size_t)r * 5;
        a[0] = a[1] = a[2] = a[3] = a[4] = 0.0f;

        float ox = ro[r * 3 + 0], oy = ro[r * 3 + 1], oz = ro[r * 3 + 2];
        float dx = rd[r * 3 + 0], dy = rd[r * 3 + 1], dz = rd[r * 3 + 2];
        float inv = __builtin_amdgcn_rsqf(dx * dx + dy * dy + dz * dz);
        float x = dx * inv, y = dy * inv, z = dz * inv;
        float* o = g_rays + (size_t)r * 24;
        o[0] = ox; o[1] = oy; o[2] = oz;
        o[3] = x;  o[4] = y;  o[5] = z;
        float* sh = o + 6;
        float zz = z * z, xx = x * x, yy = y * y;
        sh[0]  = 0.282095f;
        sh[1]  = 0.488603f * y;
        sh[2]  = 0.488603f * z;
        sh[3]  = 0.488603f * x;
        sh[4]  = 1.092548f * x * y;
        sh[5]  = 1.092548f * y * z;
        sh[6]  = 0.315392f * (3.0f * zz - 1.0f);
        sh[7]  = 1.092548f * x * z;
        sh[8]  = 0.546274f * (xx - yy);
        sh[9]  = 0.590044f * y * (3.0f * xx - yy);
        sh[10] = 2.890611f * x * y * z;
        sh[11] = 0.457046f * y * (5.0f * zz - 1.0f);
        sh[12] = 0.373176f * z * (5.0f * zz - 3.0f);
        sh[13] = 0.457046f * x * (5.0f * zz - 1.0f);
        sh[14] = 1.445306f * z * (xx - yy);
        sh[15] = 0.590044f * x * (xx - 3.0f * yy);
    } else {
        int pb = blockIdx.x - 16;
        int n  = pb * 256 + threadIdx.x;        // [0, NPTS_PAD)
        int j  = n >> 1, b = n & 1;
        float* o = g_geo + (size_t)j * 16;
        float* c = g_shc + (size_t)j * 96;
        float op = 0.0f;
        if (n < NPTS) {
            o[0 + b] = pos[n * 3 + 0];
            o[2 + b] = pos[n * 3 + 1];
            o[4 + b] = pos[n * 3 + 2];
            int s = sidx[n];
            op = fast_sigmoid(raw_op[n]);
            o[6 + b] = -__expf(log_delta[s]) * LOG2E;
            o[8 + b] =  __expf(log_sigma[s]) * op;
            const float* src = shc + (size_t)n * 48;
#pragma unroll
            for (int i = 0; i < 48; ++i) c[i * 2 + b] = src[i];
        } else {
            o[0 + b] = 1e3f; o[2 + b] = 1e3f; o[4 + b] = 1e3f;
            o[6 + b] = 0.0f; o[8 + b] = 0.0f;   // w0=0 -> zero contribution
#pragma unroll
            for (int i = 0; i < 48; ++i) c[i * 2 + b] = 0.0f;
        }
        // block-level opacity sum -> g_oppart[pb] (no global atomics needed)
        __shared__ float blk;
        if (threadIdx.x == 0) blk = 0.0f;
        __syncthreads();
        float v = op;
#pragma unroll
        for (int off = 32; off > 0; off >>= 1) v += __shfl_down(v, off, 64);
        if ((threadIdx.x & 63) == 0) atomicAdd(&blk, v);
        __syncthreads();
        if (threadIdx.x == 0) g_oppart[pb] = blk;
    }
}

// ---------------- Kernel 2: main — packed f32, 2 points/iteration ------------
__global__ __launch_bounds__(256) void nerf_main() {
    int rb = blockIdx.x & 15;     // 16 ray blocks of 256 rays
    int ch = blockIdx.x >> 4;     // CHUNKS point chunks
    int r  = rb * 256 + threadIdx.x;

    const float* rp = g_rays + (size_t)r * 24;
    v2 ox2 = v2splat(rp[0]), oy2 = v2splat(rp[1]), oz2 = v2splat(rp[2]);
    v2 dx2 = v2splat(rp[3]), dy2 = v2splat(rp[4]), dz2 = v2splat(rp[5]);
    v2 sh2[16];
#pragma unroll
    for (int k = 0; k < 16; ++k) sh2[k] = v2splat(rp[6 + k]);

    const v2 one2  = v2splat(1.0f);
    const v2 nl2e  = v2splat(-LOG2E);

    int j0 = ch * PAIRS, j1 = j0 + PAIRS;

    v2 S = v2splat(0.0f), Sd = S, Sr = S, Sg = S, Sb = S;
    for (int j = j0; j < j1; ++j) {
        const v2* q = (const v2*)(g_geo + (size_t)j * 16);   // wave-uniform
        v2 px = q[0], py = q[1], pz = q[2], w1 = q[3], w0 = q[4];

        v2 rx = px - ox2, ry = py - oy2, rz = pz - oz2;
        v2 d2 = rx * rx; d2 = fmav(ry, ry, d2); d2 = fmav(rz, rz, d2);
        v2 inv  = rsqv(d2);
        v2 dist = d2 * inv;
        v2 dn = rx * dx2; dn = fmav(ry, dy2, dn); dn = fmav(rz, dz2, dn);
        v2 t  = one2 - dn * inv;
        v2 e  = exp2v(w1 * t * t);
        v2 contrib = e * w0 * inv;

        S  = S + contrib;
        Sd = fmav(dist, contrib, Sd);

        const v2* c = (const v2*)(g_shc + (size_t)j * 96);   // wave-uniform
        v2 s0 = c[0] * sh2[0], s1 = c[1] * sh2[0], s2 = c[2] * sh2[0];
#pragma unroll
        for (int k = 1; k < 16; ++k) {
            s0 = fmav(c[k * 3 + 0], sh2[k], s0);
            s1 = fmav(c[k * 3 + 1], sh2[k], s1);
            s2 = fmav(c[k * 3 + 2], sh2[k], s2);
        }
        v2 a0 = one2 + exp2v(s0 * nl2e);
        v2 a1 = one2 + exp2v(s1 * nl2e);
        v2 a2 = one2 + exp2v(s2 * nl2e);
        v2 ab  = a0 * a1;
        v2 CI  = contrib * rcpv(ab * a2);
        Sr = fmav(CI, a1 * a2, Sr);
        Sg = fmav(CI, a0 * a2, Sg);
        Sb = fmav(CI, ab, Sb);
    }

    float* a = g_acc + (size_t)r * 5;
    atomicAdd(a + 0, Sr.x + Sr.y);
    atomicAdd(a + 1, Sg.x + Sg.y);
    atomicAdd(a + 2, Sb.x + Sb.y);
    atomicAdd(a + 3, Sd.x + Sd.y);
    atomicAdd(a + 4, S.x  + S.y);
}

// ---------------- Kernel 3: finalize (f32 output) ----------------------------
__global__ void finalize(float* __restrict__ out) {
    int r = blockIdx.x * blockDim.x + threadIdx.x;
    if (r >= NRAYS) return;
    float opv = 0.0f;
#pragma unroll
    for (int i = 0; i < PT_BLOCKS; ++i) opv += g_oppart[i];
    const float* a = g_acc + (size_t)r * 5;
    float inv = fast_rcp(a[4] + 1e-8f);
    out[r * 3 + 0]     = a[0] * inv;
    out[r * 3 + 1]     = a[1] * inv;
    out[r * 3 + 2]     = a[2] * inv;
    out[NRAYS * 3 + r] = a[3] * inv;
    out[NRAYS * 4 + r] = opv * (1.0f / NPTS);
}

extern "C" void kernel_launch(void* const* d_in, const int* in_sizes, int n_in,
                              void* d_out, int out_size, void* d_ws, size_t ws_size,
                              hipStream_t stream) {
    const float* rays_o    = (const float*)d_in[0];
    const float* rays_d    = (const float*)d_in[1];
    const float* positions = (const float*)d_in[2];
    const int*   sidx      = (const int*)d_in[3];
    const float* log_delta = (const float*)d_in[4];
    const float* log_sigma = (const float*)d_in[5];
    const float* raw_op    = (const float*)d_in[6];
    const float* shc       = (const float*)d_in[7];

    setup<<<16 + PT_BLOCKS, 256, 0, stream>>>(
        rays_o, rays_d, positions, sidx, log_delta, log_sigma, raw_op, shc);
    nerf_main<<<16 * CHUNKS, 256, 0, stream>>>();
    finalize<<<NRAYS / 256, 256, 0, stream>>>((float*)d_out);
}